// Round 1
// baseline (129.414 us; speedup 1.0000x reference)
//
#include <hip/hip_runtime.h>
#include <hip/hip_bf16.h>

#define NN 8192
#define EE 524288
#define D_IN 3
#define D_HID 16
#define D_OUT 16

// ---------------- kernel 1: zero the aggregation buffer ----------------
__global__ void zero_agg_kernel(float* __restrict__ agg, int n) {
    int i = blockIdx.x * blockDim.x + threadIdx.x;
    if (i < n) agg[i] = 0.0f;
}

// ---------------- kernel 2: edge scatter-add (GIN aggregation) ----------------
__global__ void scatter_kernel(const float* __restrict__ nf,
                               const int* __restrict__ eidx,
                               float* __restrict__ agg) {
    int e = blockIdx.x * blockDim.x + threadIdx.x;
    if (e >= EE) return;
    int s = eidx[e];          // src row
    int d = eidx[EE + e];     // dst row
    float x0 = nf[s * 3 + 0];
    float x1 = nf[s * 3 + 1];
    float x2 = nf[s * 3 + 2];
    atomicAdd(&agg[d * 3 + 0], x0);
    atomicAdd(&agg[d * 3 + 1], x1);
    atomicAdd(&agg[d * 3 + 2], x2);
}

// ---------------- kernel 3: per-node MLP -> scalar h[i] ----------------
__global__ void mlp_kernel(const float* __restrict__ nf,
                           const float* __restrict__ agg,
                           const float* __restrict__ epsp,
                           const float* __restrict__ W1, const float* __restrict__ b1,
                           const float* __restrict__ W2, const float* __restrict__ b2,
                           const float* __restrict__ W3, const float* __restrict__ b3,
                           float* __restrict__ h) {
    int i = blockIdx.x * blockDim.x + threadIdx.x;
    if (i >= NN) return;
    float eps1 = 1.0f + epsp[0];
    float z0 = eps1 * nf[i * 3 + 0] + agg[i * 3 + 0];
    float z1 = eps1 * nf[i * 3 + 1] + agg[i * 3 + 1];
    float z2 = eps1 * nf[i * 3 + 2] + agg[i * 3 + 2];

    float h1[D_HID];
#pragma unroll
    for (int j = 0; j < D_HID; ++j) {
        float v = b1[j] + z0 * W1[0 * D_HID + j] + z1 * W1[1 * D_HID + j] + z2 * W1[2 * D_HID + j];
        h1[j] = v > 0.0f ? v : 0.0f;
    }
    float h2[D_OUT];
#pragma unroll
    for (int j = 0; j < D_OUT; ++j) {
        float v = b2[j];
#pragma unroll
        for (int k = 0; k < D_HID; ++k) v += h1[k] * W2[k * D_OUT + j];
        h2[j] = v > 0.0f ? v : 0.0f;
    }
    float v = b3[0];
#pragma unroll
    for (int k = 0; k < D_OUT; ++k) v += h2[k] * W3[k];
    h[i] = v > 0.0f ? v : 0.0f;
}

// ---------------- kernel 4: outer product out[i][j] = h[i]*h[j] ----------------
// One block per row; 256 threads write 2048 float4 (32 KB) per row.
__global__ void outer_kernel(const float* __restrict__ h, float4* __restrict__ out) {
    int i = blockIdx.x;
    float hi = h[i];
    const float4* __restrict__ h4 = reinterpret_cast<const float4*>(h);
    float4* __restrict__ row = out + (size_t)i * (NN / 4);
#pragma unroll 4
    for (int j = threadIdx.x; j < NN / 4; j += 256) {
        float4 v = h4[j];
        float4 o;
        o.x = hi * v.x; o.y = hi * v.y; o.z = hi * v.z; o.w = hi * v.w;
        row[j] = o;
    }
}

extern "C" void kernel_launch(void* const* d_in, const int* in_sizes, int n_in,
                              void* d_out, int out_size, void* d_ws, size_t ws_size,
                              hipStream_t stream) {
    const float* nf   = (const float*)d_in[0];
    const int*   eidx = (const int*)d_in[1];
    const float* eps  = (const float*)d_in[2];
    const float* W1   = (const float*)d_in[3];
    const float* b1   = (const float*)d_in[4];
    const float* W2   = (const float*)d_in[5];
    const float* b2   = (const float*)d_in[6];
    const float* W3   = (const float*)d_in[7];
    const float* b3   = (const float*)d_in[8];
    float* out = (float*)d_out;

    float* agg = (float*)d_ws;                 // N*3 floats
    float* h   = agg + (size_t)NN * 3;         // N floats

    // 1. zero agg
    {
        int n = NN * 3;
        zero_agg_kernel<<<(n + 255) / 256, 256, 0, stream>>>(agg, n);
    }
    // 2. scatter-add
    scatter_kernel<<<(EE + 255) / 256, 256, 0, stream>>>(nf, eidx, agg);
    // 3. MLP
    mlp_kernel<<<(NN + 255) / 256, 256, 0, stream>>>(nf, agg, eps, W1, b1, W2, b2, W3, b3, h);
    // 4. outer product
    outer_kernel<<<NN, 256, 0, stream>>>(h, (float4*)out);
}

// Round 2
// 79.988 us; speedup vs baseline: 1.6179x; 1.6179x over previous
//
#include <hip/hip_runtime.h>
#include <hip/hip_bf16.h>

#define NN 8192
#define EE 524288
#define D_IN 3
#define D_HID 16
#define D_OUT 16
#define NAGG (NN * D_IN)   // 24576 floats
#define NB_PRIV 128        // partial-aggregation blocks

// ---------------- scatter, LDS-privatized: each block builds a full private
// agg copy in 96 KB LDS, then streams it to d_ws as a partial ----------------
__global__ __launch_bounds__(1024) void scatter_priv_kernel(
        const float* __restrict__ nf,
        const int* __restrict__ eidx,
        float* __restrict__ partials) {
    extern __shared__ float lagg[];  // NAGG floats = 96 KB
    const int tid = threadIdx.x;
    for (int i = tid; i < NAGG; i += 1024) lagg[i] = 0.0f;
    __syncthreads();

    const int per_block = EE / NB_PRIV;           // 4096 edges
    const int base = blockIdx.x * per_block;
    for (int e = base + tid; e < base + per_block; e += 1024) {
        int s = eidx[e];          // src row
        int d = eidx[EE + e];     // dst row
        atomicAdd(&lagg[d * 3 + 0], nf[s * 3 + 0]);
        atomicAdd(&lagg[d * 3 + 1], nf[s * 3 + 1]);
        atomicAdd(&lagg[d * 3 + 2], nf[s * 3 + 2]);
    }
    __syncthreads();

    float* __restrict__ my = partials + (size_t)blockIdx.x * NAGG;
    for (int i = tid; i < NAGG; i += 1024) my[i] = lagg[i];
}

// ---------------- reduce the NB_PRIV partials into agg ----------------
__global__ void reduce_partials_kernel(const float* __restrict__ partials,
                                       float* __restrict__ agg) {
    int i = blockIdx.x * blockDim.x + threadIdx.x;
    if (i >= NAGG) return;
    float s = 0.0f;
#pragma unroll 4
    for (int b = 0; b < NB_PRIV; ++b) s += partials[(size_t)b * NAGG + i];
    agg[i] = s;
}

// ---------------- fallback path (ws too small): zero + global atomics -------
__global__ void zero_agg_kernel(float* __restrict__ agg, int n) {
    int i = blockIdx.x * blockDim.x + threadIdx.x;
    if (i < n) agg[i] = 0.0f;
}

__global__ void scatter_atomic_kernel(const float* __restrict__ nf,
                                      const int* __restrict__ eidx,
                                      float* __restrict__ agg) {
    int e = blockIdx.x * blockDim.x + threadIdx.x;
    if (e >= EE) return;
    int s = eidx[e];
    int d = eidx[EE + e];
    atomicAdd(&agg[d * 3 + 0], nf[s * 3 + 0]);
    atomicAdd(&agg[d * 3 + 1], nf[s * 3 + 1]);
    atomicAdd(&agg[d * 3 + 2], nf[s * 3 + 2]);
}

// ---------------- per-node MLP -> scalar h[i] ----------------
__global__ void mlp_kernel(const float* __restrict__ nf,
                           const float* __restrict__ agg,
                           const float* __restrict__ epsp,
                           const float* __restrict__ W1, const float* __restrict__ b1,
                           const float* __restrict__ W2, const float* __restrict__ b2,
                           const float* __restrict__ W3, const float* __restrict__ b3,
                           float* __restrict__ h) {
    int i = blockIdx.x * blockDim.x + threadIdx.x;
    if (i >= NN) return;
    float eps1 = 1.0f + epsp[0];
    float z0 = eps1 * nf[i * 3 + 0] + agg[i * 3 + 0];
    float z1 = eps1 * nf[i * 3 + 1] + agg[i * 3 + 1];
    float z2 = eps1 * nf[i * 3 + 2] + agg[i * 3 + 2];

    float h1[D_HID];
#pragma unroll
    for (int j = 0; j < D_HID; ++j) {
        float v = b1[j] + z0 * W1[0 * D_HID + j] + z1 * W1[1 * D_HID + j] + z2 * W1[2 * D_HID + j];
        h1[j] = v > 0.0f ? v : 0.0f;
    }
    float h2[D_OUT];
#pragma unroll
    for (int j = 0; j < D_OUT; ++j) {
        float v = b2[j];
#pragma unroll
        for (int k = 0; k < D_HID; ++k) v += h1[k] * W2[k * D_OUT + j];
        h2[j] = v > 0.0f ? v : 0.0f;
    }
    float v = b3[0];
#pragma unroll
    for (int k = 0; k < D_OUT; ++k) v += h2[k] * W3[k];
    h[i] = v > 0.0f ? v : 0.0f;
}

// ---------------- outer product out[i][j] = h[i]*h[j] ----------------
__global__ void outer_kernel(const float* __restrict__ h, float4* __restrict__ out) {
    int i = blockIdx.x;
    float hi = h[i];
    const float4* __restrict__ h4 = reinterpret_cast<const float4*>(h);
    float4* __restrict__ row = out + (size_t)i * (NN / 4);
#pragma unroll 4
    for (int j = threadIdx.x; j < NN / 4; j += 256) {
        float4 v = h4[j];
        float4 o;
        o.x = hi * v.x; o.y = hi * v.y; o.z = hi * v.z; o.w = hi * v.w;
        row[j] = o;
    }
}

extern "C" void kernel_launch(void* const* d_in, const int* in_sizes, int n_in,
                              void* d_out, int out_size, void* d_ws, size_t ws_size,
                              hipStream_t stream) {
    const float* nf   = (const float*)d_in[0];
    const int*   eidx = (const int*)d_in[1];
    const float* eps  = (const float*)d_in[2];
    const float* W1   = (const float*)d_in[3];
    const float* b1   = (const float*)d_in[4];
    const float* W2   = (const float*)d_in[5];
    const float* b2   = (const float*)d_in[6];
    const float* W3   = (const float*)d_in[7];
    const float* b3   = (const float*)d_in[8];
    float* out = (float*)d_out;

    float* agg      = (float*)d_ws;                       // NAGG floats
    float* h        = agg + NAGG;                         // NN floats
    float* partials = h + NN;                             // NB_PRIV*NAGG floats

    size_t need = (size_t)(NAGG + NN + (size_t)NB_PRIV * NAGG) * sizeof(float);

    if (ws_size >= need) {
        scatter_priv_kernel<<<NB_PRIV, 1024, NAGG * sizeof(float), stream>>>(nf, eidx, partials);
        reduce_partials_kernel<<<(NAGG + 255) / 256, 256, 0, stream>>>(partials, agg);
    } else {
        zero_agg_kernel<<<(NAGG + 255) / 256, 256, 0, stream>>>(agg, NAGG);
        scatter_atomic_kernel<<<(EE + 255) / 256, 256, 0, stream>>>(nf, eidx, agg);
    }
    mlp_kernel<<<(NN + 255) / 256, 256, 0, stream>>>(nf, agg, eps, W1, b1, W2, b2, W3, b3, h);
    outer_kernel<<<NN, 256, 0, stream>>>(h, (float4*)out);
}